// Round 5
// baseline (188.992 us; speedup 1.0000x reference)
//
#include <hip/hip_runtime.h>

// KANStressPredictor v5: ALL buffers fp32 (exactly as the reference file says).
// Dtype forensics across rounds: r2 (bf16-read) NaN'd via fp32-mantissa-half
// decode -> log(neg); r3/r4 (fp32-read, bf16-PACKED stores) filled only the
// first half of the fp32 out buffer -> untouched second half held ref's argmax
// -> absmax == max|ref| exactly, twice, deterministically. Output is fp32.
// out0 = (eig0 * J^(-1/3))^ki0, out1 = (eig1 * J^(-1/3))^ki0, out2 = log(J)*ki1
// C = [[2s0+1, s2],[s2, 2s1+1]], eig = sqrt(eigvals(C)) ascending, J = sqrt(det C).
// Memory-bound: 100.7 MB in + 100.7 MB out = 201.3 MB -> ~32 us floor @ 6.3 TB/s.
// NOTE: __builtin_log2f/exp2f, NOT __log2f/__exp2f (glibc math.h host-pass collision).

__device__ __forceinline__ void compute3(float s0, float s1, float s2,
                                         float ki0, float ki1,
                                         float& o0, float& o1, float& o2) {
    const float c00 = __builtin_fmaf(2.0f, s0, 1.0f);
    const float c11 = __builtin_fmaf(2.0f, s1, 1.0f);
    const float c01 = s2;
    const float det = c00 * c11 - c01 * c01;          // det(C) > 0 (SPD)
    const float l2det = __builtin_log2f(det);
    const float mean = 0.5f * (c00 + c11);
    const float diff = 0.5f * (c00 - c11);
    const float rad  = __builtin_sqrtf(__builtin_fmaf(diff, diff, c01 * c01));
    const float l2a = -0.16666666667f * l2det;        // log2(det^(-1/6))
    // (sqrt(sq_eig) * aux)^ki0 = exp2(ki0*(0.5*log2(sq_eig) + l2a))
    o0 = __builtin_exp2f(ki0 * __builtin_fmaf(0.5f, __builtin_log2f(mean - rad), l2a));
    o1 = __builtin_exp2f(ki0 * __builtin_fmaf(0.5f, __builtin_log2f(mean + rad), l2a));
    // log(J) = 0.5*ln(det) = 0.5*ln2 * log2(det)
    o2 = (0.34657359028f * l2det) * ki1;
}

__global__ __launch_bounds__(256) void kan_v5_allfp32(
    const float* __restrict__ strain,
    const float* __restrict__ ki0p,
    const float* __restrict__ ki1p,
    float* __restrict__ out,
    long long ntrip)
{
    const float ki0 = ki0p[0];
    const float ki1 = ki1p[0];

    const long long nvec = ntrip >> 3;  // 8 triplets: 96 B in, 96 B out per thread
    const long long stride = (long long)gridDim.x * 256LL;

    for (long long v = (long long)blockIdx.x * 256LL + threadIdx.x; v < nvec; v += stride) {
        const float4* ip = (const float4*)(strain + v * 24);  // byte offset v*96: 16-B aligned
        const float4 f0 = ip[0], f1 = ip[1], f2 = ip[2];
        const float4 f3 = ip[3], f4 = ip[4], f5 = ip[5];

        float o[24];
        compute3(f0.x, f0.y, f0.z, ki0, ki1, o[0],  o[1],  o[2]);
        compute3(f0.w, f1.x, f1.y, ki0, ki1, o[3],  o[4],  o[5]);
        compute3(f1.z, f1.w, f2.x, ki0, ki1, o[6],  o[7],  o[8]);
        compute3(f2.y, f2.z, f2.w, ki0, ki1, o[9],  o[10], o[11]);
        compute3(f3.x, f3.y, f3.z, ki0, ki1, o[12], o[13], o[14]);
        compute3(f3.w, f4.x, f4.y, ki0, ki1, o[15], o[16], o[17]);
        compute3(f4.z, f4.w, f5.x, ki0, ki1, o[18], o[19], o[20]);
        compute3(f5.y, f5.z, f5.w, ki0, ki1, o[21], o[22], o[23]);

        float4* op = (float4*)(out + v * 24);  // byte offset v*96: 16-B aligned
        op[0] = make_float4(o[0],  o[1],  o[2],  o[3]);
        op[1] = make_float4(o[4],  o[5],  o[6],  o[7]);
        op[2] = make_float4(o[8],  o[9],  o[10], o[11]);
        op[3] = make_float4(o[12], o[13], o[14], o[15]);
        op[4] = make_float4(o[16], o[17], o[18], o[19]);
        op[5] = make_float4(o[20], o[21], o[22], o[23]);
    }

    // scalar tail (ntrip % 8 leftover triplets)
    const long long tail_start = nvec << 3;
    for (long long e = tail_start + (long long)blockIdx.x * 256LL + threadIdx.x;
         e < ntrip; e += stride) {
        float o0, o1, o2;
        compute3(strain[3 * e], strain[3 * e + 1], strain[3 * e + 2],
                 ki0, ki1, o0, o1, o2);
        out[3 * e]     = o0;
        out[3 * e + 1] = o1;
        out[3 * e + 2] = o2;
    }
}

extern "C" void kernel_launch(void* const* d_in, const int* in_sizes, int n_in,
                              void* d_out, int out_size, void* d_ws, size_t ws_size,
                              hipStream_t stream) {
    const float* strain = (const float*)d_in[0];
    const float* ki0p   = (const float*)d_in[1];
    const float* ki1p   = (const float*)d_in[2];
    float* out = (float*)d_out;

    const long long ntrip = (long long)in_sizes[0] / 3;
    const long long nvec  = ntrip >> 3;
    long long want_blocks = (nvec + 255) / 256;
    if (want_blocks < 1) want_blocks = 1;
    if (want_blocks > 65535) want_blocks = 65535;

    kan_v5_allfp32<<<(int)want_blocks, 256, 0, stream>>>(strain, ki0p, ki1p, out, ntrip);
}

// Round 6
// 180.480 us; speedup vs baseline: 1.0472x; 1.0472x over previous
//
#include <hip/hip_runtime.h>

// KANStressPredictor v6: LDS-staged coalesced layout.
// r5 post-mortem: correct (all-fp32) but 69us @ 2.18 TB/s (27% peak), VALU 20%
// -> uncoalesced: 8-triplet/thread gave 96B-stride lane addresses, ~48 lines
// touched per wave mem instruction (vs 8 ideal). Fix: tile of 2048 triplets
// (24KB) per 256-thread block; global loads/stores are lane-contiguous float4
// (16B/lane, 1KB/wave/instr); AoS->per-thread-row transpose through LDS with
// padded rows (6 data float4 + 1 pad = 112B row stride -> 8-lane groups cover
// all 32 banks; 2-way alias is free per m136).
// Math: C=[[2s0+1,s2],[s2,2s1+1]]; out=( (sqrt(eig)*det^(-1/6))^ki0 , log(J)*ki1 )
// Memory-bound: 201.3 MB total -> ~32us floor @ 6.3 TB/s.
// NOTE: __builtin_log2f/exp2f, NOT __log2f/__exp2f (glibc math.h host-pass collision).

typedef unsigned int u32;

__device__ __forceinline__ void compute3(float s0, float s1, float s2,
                                         float ki0, float ki1,
                                         float& o0, float& o1, float& o2) {
    const float c00 = __builtin_fmaf(2.0f, s0, 1.0f);
    const float c11 = __builtin_fmaf(2.0f, s1, 1.0f);
    const float c01 = s2;
    const float det = c00 * c11 - c01 * c01;          // det(C) > 0 (SPD)
    const float l2det = __builtin_log2f(det);
    const float mean = 0.5f * (c00 + c11);
    const float diff = 0.5f * (c00 - c11);
    const float rad  = __builtin_sqrtf(__builtin_fmaf(diff, diff, c01 * c01));
    const float l2a = -0.16666666667f * l2det;        // log2(det^(-1/6))
    o0 = __builtin_exp2f(ki0 * __builtin_fmaf(0.5f, __builtin_log2f(mean - rad), l2a));
    o1 = __builtin_exp2f(ki0 * __builtin_fmaf(0.5f, __builtin_log2f(mean + rad), l2a));
    o2 = (0.34657359028f * l2det) * ki1;              // log(J)=0.5*ln2*l2det
}

constexpr int TPB       = 256;
constexpr int TRIPT     = 8;                  // triplets per thread
constexpr int TILE_TRIP = TPB * TRIPT;        // 2048 triplets per block tile
constexpr int CHT       = 6;                  // float4 chunks per thread (96 B)
constexpr int TILE_CH   = TPB * CHT;          // 1536 float4 per tile
constexpr int ROW_SLOTS = 7;                  // 6 data + 1 pad slot (112 B row)

__global__ __launch_bounds__(TPB) void kan_v6_lds(
    const float* __restrict__ strain,
    const float* __restrict__ ki0p,
    const float* __restrict__ ki1p,
    float* __restrict__ out,
    long long ntrip)
{
    __shared__ float4 lds4[TPB * ROW_SLOTS];  // 28,672 B -> 5 blocks/CU

    const float ki0 = ki0p[0];
    const float ki1 = ki1p[0];
    const int t = threadIdx.x;
    const long long full_tiles = ntrip / TILE_TRIP;

    for (long long tile = blockIdx.x; tile < full_tiles; tile += gridDim.x) {
        const long long cbase = tile * TILE_CH;
        const float4* in4 = (const float4*)strain + cbase;
        float4*      out4 = (float4*)out + cbase;

        __syncthreads();  // WAR vs previous iteration's stage-out readers
#pragma unroll
        for (int j = 0; j < CHT; ++j) {
            const u32 k = (u32)t + (u32)(j * TPB);          // lane-contiguous
            lds4[(k / 6u) * ROW_SLOTS + (k % 6u)] = in4[k]; // padded scatter
        }
        __syncthreads();

        const int rb = t * ROW_SLOTS;
        const float4 r0 = lds4[rb + 0], r1 = lds4[rb + 1], r2 = lds4[rb + 2];
        const float4 r3 = lds4[rb + 3], r4 = lds4[rb + 4], r5 = lds4[rb + 5];

        float o[24];
        compute3(r0.x, r0.y, r0.z, ki0, ki1, o[0],  o[1],  o[2]);
        compute3(r0.w, r1.x, r1.y, ki0, ki1, o[3],  o[4],  o[5]);
        compute3(r1.z, r1.w, r2.x, ki0, ki1, o[6],  o[7],  o[8]);
        compute3(r2.y, r2.z, r2.w, ki0, ki1, o[9],  o[10], o[11]);
        compute3(r3.x, r3.y, r3.z, ki0, ki1, o[12], o[13], o[14]);
        compute3(r3.w, r4.x, r4.y, ki0, ki1, o[15], o[16], o[17]);
        compute3(r4.z, r4.w, r5.x, ki0, ki1, o[18], o[19], o[20]);
        compute3(r5.y, r5.z, r5.w, ki0, ki1, o[21], o[22], o[23]);

        __syncthreads();  // WAR: all row reads done before overwrite
        lds4[rb + 0] = make_float4(o[0],  o[1],  o[2],  o[3]);
        lds4[rb + 1] = make_float4(o[4],  o[5],  o[6],  o[7]);
        lds4[rb + 2] = make_float4(o[8],  o[9],  o[10], o[11]);
        lds4[rb + 3] = make_float4(o[12], o[13], o[14], o[15]);
        lds4[rb + 4] = make_float4(o[16], o[17], o[18], o[19]);
        lds4[rb + 5] = make_float4(o[20], o[21], o[22], o[23]);
        __syncthreads();

#pragma unroll
        for (int j = 0; j < CHT; ++j) {
            const u32 k = (u32)t + (u32)(j * TPB);
            out4[k] = lds4[(k / 6u) * ROW_SLOTS + (k % 6u)];  // lane-contiguous store
        }
    }

    // scalar tail (ntrip % 2048 leftover triplets)
    const long long tail_start = full_tiles * TILE_TRIP;
    const long long gs = (long long)gridDim.x * TPB;
    for (long long e = tail_start + (long long)blockIdx.x * TPB + t; e < ntrip; e += gs) {
        float o0, o1, o2;
        compute3(strain[3 * e], strain[3 * e + 1], strain[3 * e + 2],
                 ki0, ki1, o0, o1, o2);
        out[3 * e]     = o0;
        out[3 * e + 1] = o1;
        out[3 * e + 2] = o2;
    }
}

extern "C" void kernel_launch(void* const* d_in, const int* in_sizes, int n_in,
                              void* d_out, int out_size, void* d_ws, size_t ws_size,
                              hipStream_t stream) {
    const float* strain = (const float*)d_in[0];
    const float* ki0p   = (const float*)d_in[1];
    const float* ki1p   = (const float*)d_in[2];
    float* out = (float*)d_out;

    const long long ntrip = (long long)in_sizes[0] / 3;
    long long blocks = ntrip / TILE_TRIP;
    if (blocks < 1) blocks = 1;
    if (blocks > 32768) blocks = 32768;

    kan_v6_lds<<<(int)blocks, TPB, 0, stream>>>(strain, ki0p, ki1p, out, ntrip);
}